// Round 1
// baseline (229.765 us; speedup 1.0000x reference)
//
#include <hip/hip_runtime.h>
#include <hip/hip_bf16.h>

typedef __bf16 bf16x8 __attribute__((ext_vector_type(8)));
typedef float  f32x4  __attribute__((ext_vector_type(4)));

#define B_      64
#define C_      128
#define M_      4096
#define KCHUNK  4
#define KC      (M_ / KCHUNK)   // 1024
#define BK      64
#define NSLAB   (KC / BK)       // 16
#define LSTR    72              // LDS row stride in bf16 elems (pad 64->72: 2-way bank alias = free)

__device__ __forceinline__ unsigned short f2bf(float f) {
  // round-to-nearest-even fp32 -> bf16
  unsigned u = __builtin_bit_cast(unsigned, f);
  u += 0x7fffu + ((u >> 16) & 1u);
  return (unsigned short)(u >> 16);
}

__global__ __launch_bounds__(256) void covpool_main(
    const float* __restrict__ x, float* __restrict__ Gp, float* __restrict__ Sp) {
  __shared__ unsigned short As[2][C_ * LSTR];   // 2 x 18 KiB

  const int tid = threadIdx.x;
  const int b   = blockIdx.x >> 2;   // batch
  const int ch  = blockIdx.x & 3;    // K-chunk

  // staging mapping: thread covers 16 consecutive floats in rows r and r+64
  const int r  = tid >> 2;           // 0..63
  const int c4 = (tid & 3) << 4;     // 0,16,32,48

  const float* xp0 = x + ((size_t)(b * C_ + r) * M_) + (size_t)ch * KC + c4;
  const float* xp1 = xp0 + (size_t)64 * M_;

  // MFMA mapping: 4 waves in 2x2 quadrants of the 128x128 output
  const int lane = tid & 63;
  const int wave = tid >> 6;
  const int row0 = (wave >> 1) << 6;
  const int col0 = (wave & 1) << 6;
  const int lrow = lane & 15;
  const int quad = lane >> 4;

  f32x4 acc[4][4];
#pragma unroll
  for (int i = 0; i < 4; ++i)
#pragma unroll
    for (int j = 0; j < 4; ++j)
      acc[i][j] = (f32x4){0.f, 0.f, 0.f, 0.f};

  float sum0 = 0.f, sum1 = 0.f;

  // register double-buffer for global->LDS pipeline
  float4 regs[2][8];
#pragma unroll
  for (int q = 0; q < 4; ++q) {
    regs[0][q]     = ((const float4*)xp0)[q];
    regs[0][4 + q] = ((const float4*)xp1)[q];
  }

  for (int s = 0; s < NSLAB; ++s) {
    const int cur = s & 1;
    if (s + 1 < NSLAB) {  // prefetch next slab while we convert/compute current
      const float4* p0 = (const float4*)(xp0 + (size_t)(s + 1) * BK);
      const float4* p1 = (const float4*)(xp1 + (size_t)(s + 1) * BK);
#pragma unroll
      for (int q = 0; q < 4; ++q) {
        regs[cur ^ 1][q]     = p0[q];
        regs[cur ^ 1][4 + q] = p1[q];
      }
    }
    // convert + stage to LDS, accumulate row sums on the fly
    unsigned short* d0 = &As[cur][r * LSTR + c4];
    unsigned short* d1 = &As[cur][(64 + r) * LSTR + c4];
#pragma unroll
    for (int q = 0; q < 4; ++q) {
      float4 v = regs[cur][q];
      sum0 += (v.x + v.y) + (v.z + v.w);
      ushort4 pk0 = { f2bf(v.x), f2bf(v.y), f2bf(v.z), f2bf(v.w) };
      *(ushort4*)(d0 + q * 4) = pk0;
      float4 w = regs[cur][4 + q];
      sum1 += (w.x + w.y) + (w.z + w.w);
      ushort4 pk1 = { f2bf(w.x), f2bf(w.y), f2bf(w.z), f2bf(w.w) };
      *(ushort4*)(d1 + q * 4) = pk1;
    }
    __syncthreads();

    // G += T * T^T over this 64-wide K slab
#pragma unroll
    for (int ks = 0; ks < 2; ++ks) {
      const int koff = ks * 32 + quad * 8;
      bf16x8 af[4], bfr[4];
#pragma unroll
      for (int i = 0; i < 4; ++i)
        af[i] = *(const bf16x8*)&As[cur][(row0 + i * 16 + lrow) * LSTR + koff];
#pragma unroll
      for (int j = 0; j < 4; ++j)
        bfr[j] = *(const bf16x8*)&As[cur][(col0 + j * 16 + lrow) * LSTR + koff];
#pragma unroll
      for (int i = 0; i < 4; ++i)
#pragma unroll
        for (int j = 0; j < 4; ++j)
          acc[i][j] = __builtin_amdgcn_mfma_f32_16x16x32_bf16(af[i], bfr[j], acc[i][j], 0, 0, 0);
    }
    __syncthreads();  // one barrier/iter is enough with double-buffered LDS
  }

  // write partial G for this (chunk, batch): layout [chunk][b][128][128]
  float* gout = Gp + (((size_t)ch * B_ + b) << 14);
#pragma unroll
  for (int i = 0; i < 4; ++i)
#pragma unroll
    for (int j = 0; j < 4; ++j)
#pragma unroll
      for (int rr = 0; rr < 4; ++rr)
        gout[(size_t)(row0 + i * 16 + quad * 4 + rr) * C_ + (col0 + j * 16 + lrow)] = acc[i][j][rr];

  // combine the 4 lanes that share a row (tid^1, tid^2 stay in-row, in-wave)
  sum0 += __shfl_xor(sum0, 1); sum0 += __shfl_xor(sum0, 2);
  sum1 += __shfl_xor(sum1, 1); sum1 += __shfl_xor(sum1, 2);
  if ((tid & 3) == 0) {
    float* sout = Sp + (((size_t)ch * B_ + b) << 7);
    sout[r]      = sum0;
    sout[64 + r] = sum1;
  }
}

__global__ __launch_bounds__(256) void covpool_fix(
    const float* __restrict__ Gp, const float* __restrict__ Sp, float* __restrict__ y) {
  const int idx = blockIdx.x * 256 + threadIdx.x;
  const int bb  = idx >> 14;
  const int rem = idx & 16383;
  const int cc  = rem >> 7;
  const int dd  = rem & 127;
  float g = 0.f, sc = 0.f, sd = 0.f;
#pragma unroll
  for (int ch = 0; ch < KCHUNK; ++ch) {
    g  += Gp[(((size_t)ch * B_ + bb) << 14) + rem];
    sc += Sp[(((size_t)ch * B_ + bb) << 7) + cc];
    sd += Sp[(((size_t)ch * B_ + bb) << 7) + dd];
  }
  const float invM = 1.f / (float)M_;
  y[idx] = g * invM - (sc * invM) * (sd * invM);
}

extern "C" void kernel_launch(void* const* d_in, const int* in_sizes, int n_in,
                              void* d_out, int out_size, void* d_ws, size_t ws_size,
                              hipStream_t stream) {
  const float* x = (const float*)d_in[0];
  float* out = (float*)d_out;
  float* wsG = (float*)d_ws;                                  // KCHUNK*B*C*C fp32 = 16 MiB
  float* wsS = wsG + (size_t)KCHUNK * B_ * C_ * C_;           // KCHUNK*B*C fp32 = 128 KiB
  covpool_main<<<dim3(B_ * KCHUNK), dim3(256), 0, stream>>>(x, wsG, wsS);
  covpool_fix<<<dim3((B_ * C_ * C_) / 256), dim3(256), 0, stream>>>(wsG, wsS, out);
}

// Round 2
// 195.935 us; speedup vs baseline: 1.1727x; 1.1727x over previous
//
#include <hip/hip_runtime.h>

typedef __bf16 bf16x8 __attribute__((ext_vector_type(8)));
typedef float  f32x4  __attribute__((ext_vector_type(4)));
typedef unsigned short us8 __attribute__((ext_vector_type(8)));

#define B_      64
#define C_      128
#define M_      4096
#define KCHUNK  8
#define KC      (M_ / KCHUNK)   // 512
#define BK      64
#define NSLAB   (KC / BK)       // 8
#define LSTR    72              // bf16 elems; 144B row stride keeps ds_*_b128 16B-aligned

__device__ __forceinline__ unsigned short f2bf(float f) {
  unsigned u = __builtin_bit_cast(unsigned, f);
  u += 0x7fffu + ((u >> 16) & 1u);          // RNE fp32->bf16
  return (unsigned short)(u >> 16);
}
__device__ __forceinline__ float bf2f(unsigned short h) {
  unsigned u = ((unsigned)h) << 16;
  return __builtin_bit_cast(float, u);
}

// 512 threads = 8 waves. Wave w covers output rows (w>>2)*64 .. +63, cols (w&3)*32 .. +31.
// Staging: thread t covers rows (t>>3) and (t>>3)+64, floats [(t&7)*8, +8) of the 64-wide slab.
__global__ __launch_bounds__(512, 4) void covpool_main(
    const float* __restrict__ x, unsigned short* __restrict__ Gp, float* __restrict__ Sp) {
  __shared__ unsigned short As[2][C_ * LSTR];   // 36 KiB total -> 2 blocks/CU fits

  const int tid  = threadIdx.x;
  const int b    = blockIdx.x >> 3;
  const int ch   = blockIdx.x & 7;

  const int row  = tid >> 3;          // 0..63
  const int col8 = tid & 7;           // 8 floats each

  const float* xp0 = x + ((size_t)(b * C_ + row) * M_) + (size_t)ch * KC + col8 * 8;
  const float* xp1 = xp0 + (size_t)64 * M_;

  const int lane = tid & 63;
  const int wave = tid >> 6;
  const int row0 = (wave >> 2) << 6;  // 0 or 64
  const int col0 = (wave & 3) << 5;   // 0,32,64,96
  const int lrow = lane & 15;
  const int quad = lane >> 4;

  f32x4 acc[4][2];
#pragma unroll
  for (int i = 0; i < 4; ++i)
#pragma unroll
    for (int j = 0; j < 2; ++j)
      acc[i][j] = (f32x4){0.f, 0.f, 0.f, 0.f};

  float sum0 = 0.f, sum1 = 0.f;

  // explicit double-buffer prefetch registers (NO dynamic indexing -> no scratch)
  float4 a0, a1, a2, a3, b0, b1, b2, b3;

  a0 = ((const float4*)xp0)[0]; a1 = ((const float4*)xp0)[1];
  a2 = ((const float4*)xp1)[0]; a3 = ((const float4*)xp1)[1];

#define STAGE(BUF, R0, R1, R2, R3)                                                  \
  {                                                                                 \
    sum0 += (R0.x + R0.y) + (R0.z + R0.w) + (R1.x + R1.y) + (R1.z + R1.w);          \
    sum1 += (R2.x + R2.y) + (R2.z + R2.w) + (R3.x + R3.y) + (R3.z + R3.w);          \
    us8 v0 = { f2bf(R0.x), f2bf(R0.y), f2bf(R0.z), f2bf(R0.w),                      \
               f2bf(R1.x), f2bf(R1.y), f2bf(R1.z), f2bf(R1.w) };                    \
    us8 v1 = { f2bf(R2.x), f2bf(R2.y), f2bf(R2.z), f2bf(R2.w),                      \
               f2bf(R3.x), f2bf(R3.y), f2bf(R3.z), f2bf(R3.w) };                    \
    *(__shared__ us8*)&As[BUF][row * LSTR + col8 * 8]        = v0;                  \
    *(__shared__ us8*)&As[BUF][(64 + row) * LSTR + col8 * 8] = v1;                  \
  }

#define COMPUTE(BUF)                                                                \
  {                                                                                 \
    _Pragma("unroll")                                                               \
    for (int ks = 0; ks < 2; ++ks) {                                                \
      const int koff = ks * 32 + quad * 8;                                          \
      bf16x8 af[4], bfr[2];                                                         \
      _Pragma("unroll")                                                             \
      for (int i = 0; i < 4; ++i)                                                   \
        af[i] = *(const __shared__ bf16x8*)&As[BUF][(row0 + i * 16 + lrow) * LSTR + koff]; \
      _Pragma("unroll")                                                             \
      for (int j = 0; j < 2; ++j)                                                   \
        bfr[j] = *(const __shared__ bf16x8*)&As[BUF][(col0 + j * 16 + lrow) * LSTR + koff]; \
      _Pragma("unroll")                                                             \
      for (int i = 0; i < 4; ++i)                                                   \
        _Pragma("unroll")                                                           \
        for (int j = 0; j < 2; ++j)                                                 \
          acc[i][j] = __builtin_amdgcn_mfma_f32_16x16x32_bf16(af[i], bfr[j], acc[i][j], 0, 0, 0); \
    }                                                                               \
  }

#pragma unroll
  for (int s = 0; s < NSLAB; s += 2) {
    {  // prefetch slab s+1
      const float* p0 = xp0 + (size_t)(s + 1) * BK;
      const float* p1 = xp1 + (size_t)(s + 1) * BK;
      b0 = ((const float4*)p0)[0]; b1 = ((const float4*)p0)[1];
      b2 = ((const float4*)p1)[0]; b3 = ((const float4*)p1)[1];
    }
    STAGE(0, a0, a1, a2, a3);
    __syncthreads();
    COMPUTE(0);
    if (s + 2 < NSLAB) {  // prefetch slab s+2
      const float* p0 = xp0 + (size_t)(s + 2) * BK;
      const float* p1 = xp1 + (size_t)(s + 2) * BK;
      a0 = ((const float4*)p0)[0]; a1 = ((const float4*)p0)[1];
      a2 = ((const float4*)p1)[0]; a3 = ((const float4*)p1)[1];
    }
    STAGE(1, b0, b1, b2, b3);
    __syncthreads();
    COMPUTE(1);
  }

  // partial G (bf16), layout [ch][b][128][128]
  unsigned short* gout = Gp + (((size_t)ch * B_ + b) << 14);
#pragma unroll
  for (int i = 0; i < 4; ++i)
#pragma unroll
    for (int j = 0; j < 2; ++j)
#pragma unroll
      for (int rr = 0; rr < 4; ++rr)
        gout[(size_t)(row0 + i * 16 + quad * 4 + rr) * C_ + (col0 + j * 16 + lrow)] =
            f2bf(acc[i][j][rr]);

  // row sums: 8 lanes share a row (tid>>3), all within one wave
  sum0 += __shfl_xor(sum0, 1); sum0 += __shfl_xor(sum0, 2); sum0 += __shfl_xor(sum0, 4);
  sum1 += __shfl_xor(sum1, 1); sum1 += __shfl_xor(sum1, 2); sum1 += __shfl_xor(sum1, 4);
  if ((tid & 7) == 0) {
    float* sout = Sp + (((size_t)ch * B_ + b) << 7);
    sout[row]      = sum0;
    sout[64 + row] = sum1;
  }
}

__global__ __launch_bounds__(256) void covpool_fix(
    const unsigned short* __restrict__ Gp, const float* __restrict__ Sp,
    float* __restrict__ y) {
  const int idx = (blockIdx.x * 256 + threadIdx.x) * 4;   // 4 outputs/thread
  const int bb  = idx >> 14;
  const int rem = idx & 16383;
  const int cc  = rem >> 7;
  const int dd  = rem & 127;    // multiple of 4
  float g0 = 0.f, g1 = 0.f, g2 = 0.f, g3 = 0.f, sc = 0.f;
  float4 sd = {0.f, 0.f, 0.f, 0.f};
#pragma unroll
  for (int ch = 0; ch < KCHUNK; ++ch) {
    ushort4 gv = *(const ushort4*)&Gp[(((size_t)ch * B_ + bb) << 14) + rem];
    g0 += bf2f(gv.x); g1 += bf2f(gv.y); g2 += bf2f(gv.z); g3 += bf2f(gv.w);
    const float* sp = Sp + (((size_t)ch * B_ + bb) << 7);
    sc += sp[cc];
    float4 s4 = *(const float4*)&sp[dd];
    sd.x += s4.x; sd.y += s4.y; sd.z += s4.z; sd.w += s4.w;
  }
  const float invM = 1.f / (float)M_;
  const float scm = sc * invM;
  float4 out = { g0 * invM - scm * (sd.x * invM), g1 * invM - scm * (sd.y * invM),
                 g2 * invM - scm * (sd.z * invM), g3 * invM - scm * (sd.w * invM) };
  *(float4*)&y[idx] = out;
}

extern "C" void kernel_launch(void* const* d_in, const int* in_sizes, int n_in,
                              void* d_out, int out_size, void* d_ws, size_t ws_size,
                              hipStream_t stream) {
  const float* x = (const float*)d_in[0];
  float* out = (float*)d_out;
  unsigned short* wsG = (unsigned short*)d_ws;              // 8*64*16384 bf16 = 16.8 MB
  float* wsS = (float*)(wsG + (size_t)KCHUNK * B_ * C_ * C_); // 8*64*128 fp32 = 256 KB
  covpool_main<<<dim3(B_ * KCHUNK), dim3(512), 0, stream>>>(x, wsG, wsS);
  covpool_fix<<<dim3((B_ * C_ * C_) / 1024), dim3(256), 0, stream>>>(wsG, wsS, out);
}